// Round 1
// baseline (400.758 us; speedup 1.0000x reference)
//
#include <hip/hip_runtime.h>

// GCN 2-layer + linear head on MI355X.
// Strategy: build CSR-by-dst per call (histogram + scan + scatter),
// then per layer: GEMM64 (fused *dinv) -> per-node neighbor sum -> scale+bias+ReLU.

constexpr int TPB = 256;

// ---- CSR build ---------------------------------------------------------

__global__ void k_hist(const int* __restrict__ dst, int E, int* __restrict__ counts) {
    int i = blockIdx.x * blockDim.x + threadIdx.x;
    int stride = gridDim.x * blockDim.x;
    for (; i < E; i += stride) atomicAdd(&counts[dst[i]], 1);
}

__global__ void k_scan_partial(const int* __restrict__ counts, int n, int* __restrict__ partial) {
    __shared__ int sdata[TPB];
    int idx = blockIdx.x * TPB + threadIdx.x;
    int v = (idx < n) ? counts[idx] : 0;
    sdata[threadIdx.x] = v;
    __syncthreads();
    for (int s = TPB / 2; s > 0; s >>= 1) {
        if (threadIdx.x < s) sdata[threadIdx.x] += sdata[threadIdx.x + s];
        __syncthreads();
    }
    if (threadIdx.x == 0) partial[blockIdx.x] = sdata[0];
}

__global__ void k_scan_offsets(int* __restrict__ partial, int nb, int* __restrict__ rowptr, int n) {
    // single-thread exclusive scan over ~391 block sums (trivial cost)
    if (threadIdx.x == 0 && blockIdx.x == 0) {
        int run = 0;
        for (int b = 0; b < nb; ++b) { int t = partial[b]; partial[b] = run; run += t; }
        rowptr[n] = run;  // == E
    }
}

__global__ void k_scan_final(const int* __restrict__ counts, int n, const int* __restrict__ partial,
                             int* __restrict__ rowptr, int* __restrict__ cursor,
                             float* __restrict__ dinv) {
    __shared__ int sdata[TPB];
    int idx = blockIdx.x * TPB + threadIdx.x;
    int v = (idx < n) ? counts[idx] : 0;
    sdata[threadIdx.x] = v;
    __syncthreads();
    // inclusive Hillis-Steele scan
    for (int s = 1; s < TPB; s <<= 1) {
        int add = (threadIdx.x >= (unsigned)s) ? sdata[threadIdx.x - s] : 0;
        __syncthreads();
        sdata[threadIdx.x] += add;
        __syncthreads();
    }
    if (idx < n) {
        int exc = sdata[threadIdx.x] - v + partial[blockIdx.x];
        rowptr[idx] = exc;
        cursor[idx] = exc;
        dinv[idx] = rsqrtf(1.0f + (float)v);  // deg = 1 + in-degree
    }
}

__global__ void k_scatter(const int* __restrict__ src, const int* __restrict__ dst, int E,
                          int* __restrict__ cursor, int* __restrict__ csr) {
    int i = blockIdx.x * blockDim.x + threadIdx.x;
    int stride = gridDim.x * blockDim.x;
    for (; i < E; i += stride) {
        int d = dst[i];
        int pos = atomicAdd(&cursor[d], 1);
        csr[pos] = src[i];
    }
}

// ---- GEMM: out[i][f] = (sum_k A[i][k] * W[k][f]) * dinv[i] ------------
// One lane per output feature f; W column f in 64 VGPRs; A-row broadcast
// via v_readlane (2 VALU per FMA). Block = 4 waves, 64 rows per block.

__global__ __launch_bounds__(256) void k_gemm64(const float* __restrict__ A, const float* __restrict__ W,
                                                const float* __restrict__ dinv, float* __restrict__ out,
                                                int n) {
    const int lane = threadIdx.x & 63;
    const int wave = threadIdx.x >> 6;  // 0..3
    float wcol[64];
#pragma unroll
    for (int k = 0; k < 64; ++k) wcol[k] = W[k * 64 + lane];

    const int ROWS_PER_BLOCK = 64;
    int base = blockIdx.x * ROWS_PER_BLOCK;
    for (int r = wave; r < ROWS_PER_BLOCK; r += 4) {
        int row = base + r;
        if (row >= n) break;
        float a = A[(size_t)row * 64 + lane];
        float acc = 0.0f;
#pragma unroll
        for (int k = 0; k < 64; ++k) {
            float ak = __uint_as_float(__builtin_amdgcn_readlane(__float_as_uint(a), k));
            acc = fmaf(ak, wcol[k], acc);
        }
        out[(size_t)row * 64 + lane] = acc * dinv[row];
    }
}

// ---- Aggregate: out[i][f] = relu(dinv[i]*(g[i][f] + sum_nb g[s][f]) + b[f])

__global__ __launch_bounds__(256) void k_aggregate(const float* __restrict__ g,
                                                   const int* __restrict__ rowptr,
                                                   const int* __restrict__ csr,
                                                   const float* __restrict__ dinv,
                                                   const float* __restrict__ bias,
                                                   float* __restrict__ out, int n) {
    int t = blockIdx.x * blockDim.x + threadIdx.x;
    int node = t >> 6;
    int lane = t & 63;
    if (node >= n) return;
    int e = rowptr[node];
    int e1 = rowptr[node + 1];
    float acc = g[(size_t)node * 64 + lane];  // self-loop term
    for (; e + 4 <= e1; e += 4) {
        int i0 = csr[e], i1 = csr[e + 1], i2 = csr[e + 2], i3 = csr[e + 3];
        float a0 = g[(size_t)i0 * 64 + lane];
        float a1 = g[(size_t)i1 * 64 + lane];
        float a2 = g[(size_t)i2 * 64 + lane];
        float a3 = g[(size_t)i3 * 64 + lane];
        acc += a0 + a1 + a2 + a3;
    }
    for (; e < e1; ++e) acc += g[(size_t)csr[e] * 64 + lane];
    float v = fmaf(dinv[node], acc, bias[lane]);
    out[(size_t)node * 64 + lane] = fmaxf(v, 0.0f);
}

// ---- Final head: out[i] = sum_k h[i][k]*Wo[k] + bo ---------------------

__global__ __launch_bounds__(256) void k_final(const float* __restrict__ h, const float* __restrict__ Wo,
                                               const float* __restrict__ bo, float* __restrict__ out,
                                               int n) {
    int t = blockIdx.x * blockDim.x + threadIdx.x;
    int node = t >> 6;
    int lane = t & 63;
    if (node >= n) return;
    float p = h[(size_t)node * 64 + lane] * Wo[lane];
#pragma unroll
    for (int s = 32; s > 0; s >>= 1) p += __shfl_xor(p, s, 64);
    if (lane == 0) out[node] = p + bo[0];
}

extern "C" void kernel_launch(void* const* d_in, const int* in_sizes, int n_in,
                              void* d_out, int out_size, void* d_ws, size_t ws_size,
                              hipStream_t stream) {
    const float* x  = (const float*)d_in[0];
    const int*   ei = (const int*)d_in[1];
    const float* W1 = (const float*)d_in[2];
    const float* b1 = (const float*)d_in[3];
    const float* W2 = (const float*)d_in[4];
    const float* b2 = (const float*)d_in[5];
    const float* Wo = (const float*)d_in[6];
    const float* bo = (const float*)d_in[7];
    float* out = (float*)d_out;

    const int n = in_sizes[0] / 64;
    const int E = in_sizes[1] / 2;
    const int* src = ei;
    const int* dst = ei + E;

    char* ws = (char*)d_ws;
    size_t off = 0;
    auto alloc = [&](size_t bytes) -> void* {
        void* p = ws + off;
        off += (bytes + 255) & ~(size_t)255;
        return p;
    };
    const int nScanBlocks = (n + TPB - 1) / TPB;
    float* dinv   = (float*)alloc((size_t)n * 4);
    int*   rowptr = (int*)alloc((size_t)(n + 1) * 4);
    int*   cursor = (int*)alloc((size_t)n * 4);
    int*   counts = (int*)alloc((size_t)n * 4);
    int*   partial= (int*)alloc((size_t)nScanBlocks * 4);
    int*   csr    = (int*)alloc((size_t)E * 4);
    float* bufA   = (float*)alloc((size_t)n * 64 * 4);
    float* bufB   = (float*)alloc((size_t)n * 64 * 4);

    // ---- CSR build (also yields dinv) ----
    hipMemsetAsync(counts, 0, (size_t)n * 4, stream);
    k_hist<<<512, TPB, 0, stream>>>(dst, E, counts);
    k_scan_partial<<<nScanBlocks, TPB, 0, stream>>>(counts, n, partial);
    k_scan_offsets<<<1, 64, 0, stream>>>(partial, nScanBlocks, rowptr, n);
    k_scan_final<<<nScanBlocks, TPB, 0, stream>>>(counts, n, partial, rowptr, cursor, dinv);
    k_scatter<<<512, TPB, 0, stream>>>(src, dst, E, cursor, csr);

    const int gemmGrid = (n + 63) / 64;
    const int nodeGrid = (n * 64 + TPB - 1) / TPB;

    // ---- layer 1 ----
    k_gemm64<<<gemmGrid, TPB, 0, stream>>>(x, W1, dinv, bufA, n);
    k_aggregate<<<nodeGrid, TPB, 0, stream>>>(bufA, rowptr, csr, dinv, b1, bufB, n);
    // ---- layer 2 ----
    k_gemm64<<<gemmGrid, TPB, 0, stream>>>(bufB, W2, dinv, bufA, n);
    k_aggregate<<<nodeGrid, TPB, 0, stream>>>(bufA, rowptr, csr, dinv, b2, bufB, n);
    // ---- head ----
    k_final<<<nodeGrid, TPB, 0, stream>>>(bufB, Wo, bo, out, n);
}